// Round 5
// baseline (4165.305 us; speedup 1.0000x reference)
//
#include <hip/hip_runtime.h>
#include <math.h>

// ---------------------------------------------------------------------------
// RNN knowledge-tracing model, MI355X (gfx950).
// B=64, T=200, SKILLS=1024, C=256, H=1024.  ALL external I/O is fp32.
// Internal compute uses bf16 MFMA with fp32 accumulation.
// Round 10 = round 9 resubmit (infra failure, no counters) + hardening:
//   * Counter poll is BOUNDED (2^20 spins ~0.1s >> expected ~us wait).
//     Correct protocol never hits the bound; an unforeseen stall now ends
//     as a readable absmax failure instead of a wedged container.
// Round 9 design (unchanged):
//   * 64 blocks x 1024 threads = 4 batch-groups x 16 col-groups;
//     block = 16 batches x 64 h-cols; wave w owns batch-row w in update.
//   * Publish from registers per-wave: 2 shfl_xor pack 4 cols/u64; 16
//     lanes/wave issue returning exchanges; vmcnt(0); lane0 fetch_add(+1)
//     on the group counter.  No hbuf, publish parallel across 16 waves.
//   * Monotonic aggregate-counter barrier: poll ONE counter >= t*256
//     (256 adds/step = 16 blocks x 16 waves).  Adds happen after all
//     reads+publish => counter pass proves frame quiescent AND own block's
//     waves past their Ab/gbuf reads => 2 __syncthreads/step.
//   * Staging: 2 x 16B sc0 sc1 read-through loads/thread (32KB/block).
// ---------------------------------------------------------------------------

typedef unsigned short u16;
typedef unsigned long long u64;
typedef __bf16 bf16x8 __attribute__((ext_vector_type(8)));
typedef float floatx4 __attribute__((ext_vector_type(4)));
typedef unsigned int u32x4 __attribute__((ext_vector_type(4)));

__device__ __forceinline__ float bf2f(u16 h) {
  unsigned int u = ((unsigned int)h) << 16;
  float f;
  __builtin_memcpy(&f, &u, 4);
  return f;
}
__device__ __forceinline__ u16 f2bf(float f) {
  unsigned int u;
  __builtin_memcpy(&u, &f, 4);
  u += 0x7FFFu + ((u >> 16) & 1u);  // RNE
  return (u16)(u >> 16);
}
__device__ __forceinline__ float sigm(float x) { return 1.0f / (1.0f + __expf(-x)); }

// --- fp32 -> bf16 convert, float4 vectorized; exact grid (n % 1024 == 0) ---
__global__ void cvt_kernel(const float* __restrict__ in, u16* __restrict__ out) {
  const int i = blockIdx.x * 256 + threadIdx.x;
  const float4 v = ((const float4*)in)[i];
  ushort4 o;
  o.x = f2bf(v.x);
  o.y = f2bf(v.y);
  o.z = f2bf(v.z);
  o.w = f2bf(v.w);
  ((ushort4*)out)[i] = o;
}

// ---------------------------------------------------------------------------
// Generic 128x128-tile bf16 GEMM, C = A[M,K] @ B[N,K]^T, epilogue functor.
// ---------------------------------------------------------------------------
template <class Epi>
__global__ __launch_bounds__(256, 2) void gemm_bt(const u16* __restrict__ A,
                                                  const u16* __restrict__ B,
                                                  int M, int N, int K, Epi epi) {
  __shared__ u16 As[128 * 32];
  __shared__ u16 Bs[128 * 32];
  const int tid = threadIdx.x;
  const int w = tid >> 6, lane = tid & 63;
  const int wm = w & 1, wn = w >> 1;
  const int bm = blockIdx.x * 128, bn = blockIdx.y * 128;
  const int lrow = lane & 15, lk8 = (lane >> 4) * 8;
  const int srow = lane >> 2;        // staging: row within 16-row segment
  const int skc = (lane & 3) * 8;    // staging: k chunk (8 bf16 = 16B)

  floatx4 acc[4][4] = {};

  for (int k0 = 0; k0 < K; k0 += 32) {
#pragma unroll
    for (int r = 0; r < 2; ++r) {
      const int seg = w * 2 + r;  // 8 segments of 16 rows x 32 k
      const int row = seg * 16 + srow;
      __builtin_amdgcn_global_load_lds(
          (const __attribute__((address_space(1))) unsigned int*)(A + (size_t)(bm + row) * K + k0 + skc),
          (__attribute__((address_space(3))) unsigned int*)(As + seg * 512), 16, 0, 0);
      __builtin_amdgcn_global_load_lds(
          (const __attribute__((address_space(1))) unsigned int*)(B + (size_t)(bn + row) * K + k0 + skc),
          (__attribute__((address_space(3))) unsigned int*)(Bs + seg * 512), 16, 0, 0);
    }
    __syncthreads();

    bf16x8 af[4], bfr[4];
#pragma unroll
    for (int i = 0; i < 4; ++i) {
      af[i] = *(const bf16x8*)(As + (wm * 64 + i * 16 + lrow) * 32 + lk8);
      bfr[i] = *(const bf16x8*)(Bs + (wn * 64 + i * 16 + lrow) * 32 + lk8);
    }
#pragma unroll
    for (int i = 0; i < 4; ++i)
#pragma unroll
      for (int j = 0; j < 4; ++j)
        acc[i][j] = __builtin_amdgcn_mfma_f32_16x16x32_bf16(af[i], bfr[j], acc[i][j], 0, 0, 0);
    __syncthreads();
  }

  // C/D layout: col = lane&15, row = (lane>>4)*4 + reg  [verified m89/m91]
  const int rbase = bm + wm * 64 + (lane >> 4) * 4;
  const int cbase = bn + wn * 64 + lrow;
#pragma unroll
  for (int i = 0; i < 4; ++i)
#pragma unroll
    for (int j = 0; j < 4; ++j)
#pragma unroll
      for (int r = 0; r < 4; ++r)
        epi(rbase + i * 16 + r, cbase + j * 16, acc[i][j][r]);
}

// --- epilogues --------------------------------------------------------------
struct EpiKcVec {  // rows are b*200+t; scatter into [row][512] by result mask
  const float* bkc;
  const int* result;
  u16* kcv;
  __device__ void operator()(int row, int col, float v) const {
    v += bkc[col];
    const int off = (result[row] == 1) ? 0 : 256;
    const size_t base = (size_t)row * 512;
    kcv[base + off + col] = f2bf(v);
    kcv[base + (256 - off) + col] = 0;  // zero half
  }
};
struct EpiNk {
  const float* bkc;
  float* nk;
  __device__ void operator()(int row, int col, float v) const {
    nk[(size_t)row * 256 + col] = v + bkc[col];
  }
};
struct EpiGx {  // input row = b*200+t -> store t-major (t*64+b), bf16
  const float* bih;
  const float* bhh;
  u16* gx;
  __device__ void operator()(int row, int col, float v) const {
    v += bih[col] + bhh[col];
    const int b = row / 200, t = row - b * 200;
    gx[(size_t)(t * 64 + b) * 4096 + col] = f2bf(v);
  }
};
struct EpiStu {  // input row = t*64+b -> store fp32 at (b*200+t)*256+col
  const float* bst;
  float* out;
  __device__ void operator()(int row, int col, float v) const {
    v += bst[col];
    const int b = row & 63, t = row >> 6;
    out[(size_t)(b * 200 + t) * 256 + col] = v;
  }
};

// ---------------------------------------------------------------------------
// init: zero h frame 0 (64x1024 bf16 = 128KB) + 128 counter slots
// ---------------------------------------------------------------------------
__global__ void init_kernel(u16* hseq, unsigned* cnt) {
  const int i = blockIdx.x * 256 + threadIdx.x;  // 64 blocks -> 16384 threads
  ((u64*)hseq)[i] = 0ULL;
  if (blockIdx.x == 0 && threadIdx.x < 128) cnt[threadIdx.x] = 0u;
}

// ---------------------------------------------------------------------------
// LSTM scan. 64 blocks x 1024 threads = 4 batch-groups x 16 col-groups;
// block owns 16 batches x 64 h-cols.  Wave w (0..15): gate g = w&3,
// col-quarter cq = w>>2; its W_hh slice (16 rows x 1024 K) is loaded as 32
// MFMA B-fragments.  In the update phase wave w owns batch-row w.
//
// Fence-free h exchange:
//   publish (per wave): pack h into u64 via 2 shfl_xor; lanes (lane&3)==0
//            issue 1 relaxed AGENT u64 returning EXCHANGE (executes at the
//            coherence point); s_waitcnt vmcnt(0); lane 0 does ONE relaxed
//            AGENT fetch_add(+1) on the group counter.
//   wait:    poll the single group counter until >= t*256 (bounded spin;
//            bound ~5000x the expected wait, never hit when correct).
//            Monotonic induction: counter >= t*256 => steps < t fully at
//            the IC, and every wave (incl. my block's) is past its reads.
//   consume: frame quiescent => plain read-through loads (global_load_dwordx4
//            sc0 sc1) stage it, 2 x 16B per thread.
// ---------------------------------------------------------------------------
__global__ __launch_bounds__(1024, 1) void lstm_scan(const u16* __restrict__ Whh,
                                                     const u16* __restrict__ gx,
                                                     u16* __restrict__ hseq,
                                                     unsigned* __restrict__ cnt) {
  __shared__ __align__(16) u16 Ab[16 * 1032];  // +8 pad: 2-way bank alias (free)
  __shared__ float gbuf[4 * 16 * 64];          // [gate][row][col] = 16 KB
  const int tid = threadIdx.x;
  const int w = tid >> 6;   // wave = batch-row owner; also (g, cq) key
  const int lane = tid & 63;
  const int lrow = lane & 15;
  const int lk8 = (lane >> 4) * 8;
  const int g = w & 3;      // gate index (torch order i,f,g,o)
  const int cq = w >> 2;    // col quarter (0..3) within the block's 64 cols
  const int gb = blockIdx.x >> 4;
  const int gn = blockIdx.x & 15;
  const int bb = gb * 16;
  const int j0 = gn * 64;
  unsigned* const gcnt = cnt + gb * 16;  // 64B-spaced per-group counters

  // B-fragments: W_hh[g*1024 + j0 + cq*16 + lrow][k], loaded once
  bf16x8 bfrag[32];
  {
    const u16* wp = Whh + (size_t)(g * 1024 + j0 + cq * 16 + lrow) * 1024 + lk8;
#pragma unroll
    for (int ks = 0; ks < 32; ++ks) bfrag[ks] = *(const bf16x8*)(wp + ks * 32);
  }

  float c_state = 0.0f;

  // gx fetch: 4 values/thread (batch rows (lane>>4)*4+r, gate g, col cq*16+lrow)
  const u16* gxb =
      gx + (size_t)(bb + (lane >> 4) * 4) * 4096 + g * 1024 + j0 + cq * 16 + lrow;
  u16 gcur[4];
  {
    const u16* gp = gxb;  // t = 0
    gcur[0] = gp[0];
    gcur[1] = gp[4096];
    gcur[2] = gp[8192];
    gcur[3] = gp[12288];
  }

  for (int t = 0; t < 200; ++t) {
    // ---- wait: poll the single group counter (frame t fully published) ----
    if (t > 0) {
      const unsigned tgt = (unsigned)t * 256u;
      for (unsigned spin = 0; spin < (1u << 20); ++spin) {
        const unsigned v = __hip_atomic_load(gcnt, __ATOMIC_RELAXED,
                                             __HIP_MEMORY_SCOPE_AGENT);
        if (v >= tgt) break;
        __builtin_amdgcn_s_sleep(1);
      }
    }

    // ---- stage h[t] rows bb..bb+15 (32KB) via coherent 16B loads ----
    {
      const char* hb = (const char*)(hseq + (size_t)t * 65536 + (size_t)bb * 1024);
      const char* p0 = hb + tid * 16;
      const char* p1 = p0 + 16384;
      u32x4 t0, t1;
      asm volatile(
          "global_load_dwordx4 %0, %2, off sc0 sc1\n\t"
          "global_load_dwordx4 %1, %3, off sc0 sc1\n\t"
          "s_waitcnt vmcnt(0)"
          : "=&v"(t0), "=&v"(t1)
          : "v"(p0), "v"(p1)
          : "memory");
      // chunk ch = jj*1024 + tid: row = ch>>7 (128 chunks/row), col8 = (ch&127)*8
      {
        const int ch = tid;
        *(u32x4*)(Ab + (ch >> 7) * 1032 + (ch & 127) * 8) = t0;
      }
      {
        const int ch = 1024 + tid;
        *(u32x4*)(Ab + (ch >> 7) * 1032 + (ch & 127) * 8) = t1;
      }
    }
    __syncthreads();

    // acc init = gx (includes b_ih+b_hh); D layout col=lane&15, row=(lane>>4)*4+r
    floatx4 a0, a1 = {}, a2 = {}, a3 = {};
    a0[0] = bf2f(gcur[0]);
    a0[1] = bf2f(gcur[1]);
    a0[2] = bf2f(gcur[2]);
    a0[3] = bf2f(gcur[3]);

    // prefetch gx for t+1 now: HBM latency hides under the MFMA section
    if (t < 199) {
      const u16* gp = gxb + (size_t)(t + 1) * 262144;
      gcur[0] = gp[0];
      gcur[1] = gp[4096];
      gcur[2] = gp[8192];
      gcur[3] = gp[12288];
    }

    // 4 independent accumulator chains (dep chain 32 -> 8)
#pragma unroll
    for (int ks = 0; ks < 32; ks += 4) {
      const u16* ap = Ab + lrow * 1032 + ks * 32 + lk8;
      a0 = __builtin_amdgcn_mfma_f32_16x16x32_bf16(*(const bf16x8*)(ap), bfrag[ks], a0, 0, 0, 0);
      a1 = __builtin_amdgcn_mfma_f32_16x16x32_bf16(*(const bf16x8*)(ap + 32), bfrag[ks + 1], a1, 0, 0, 0);
      a2 = __builtin_amdgcn_mfma_f32_16x16x32_bf16(*(const bf16x8*)(ap + 64), bfrag[ks + 2], a2, 0, 0, 0);
      a3 = __builtin_amdgcn_mfma_f32_16x16x32_bf16(*(const bf16x8*)(ap + 96), bfrag[ks + 3], a3, 0, 0, 0);
    }
    const floatx4 acc = (a0 + a1) + (a2 + a3);
    {
      const int mrow = (lane >> 4) * 4;
#pragma unroll
      for (int r = 0; r < 4; ++r)
        gbuf[g * 1024 + (mrow + r) * 64 + cq * 16 + lrow] = acc[r];
    }
    __syncthreads();

    // update phase: wave w = batch-row w, lane = col
    const float gi = gbuf[w * 64 + lane];
    const float gf = gbuf[1024 + w * 64 + lane];
    const float gg = gbuf[2048 + w * 64 + lane];
    const float go = gbuf[3072 + w * 64 + lane];
    c_state = sigm(gf) * c_state + sigm(gi) * tanhf(gg);
    const float h = sigm(go) * tanhf(c_state);

    // ---- publish h[t+1] from registers: 2 shfl_xor pack, 16 exchanges/wave --
    {
      const unsigned hb16 = (unsigned)f2bf(h);
      const unsigned nb = (unsigned)__shfl_xor((int)hb16, 1, 64);
      const unsigned lo = (lane & 1) ? (nb | (hb16 << 16)) : (hb16 | (nb << 16));
      const unsigned hi = (unsigned)__shfl_xor((int)lo, 2, 64);
      if ((lane & 3) == 0) {
        const u64 word = (u64)lo | ((u64)hi << 32);
        u64* dst = (u64*)(hseq + (size_t)(t + 1) * 65536 + (size_t)(bb + w) * 1024 + j0) +
                   (lane >> 2);
        u64 old = __hip_atomic_exchange(dst, word, __ATOMIC_RELAXED,
                                        __HIP_MEMORY_SCOPE_AGENT);
        asm volatile("" ::"v"(old));  // force sc0 (returning) form
      }
      asm volatile("s_waitcnt vmcnt(0)" ::: "memory");  // returns back => h at IC
      if (lane == 0) {
        unsigned o = __hip_atomic_fetch_add(gcnt, 1u, __ATOMIC_RELAXED,
                                            __HIP_MEMORY_SCOPE_AGENT);
        asm volatile("" ::"v"(o));
      }
    }
    // No extra sync: next-iter Ab/gbuf overwrites are gated by the counter
    // (every wave's add happens only after its reads of this step).
  }
}

// ---------------------------------------------------------------------------
// res[b*200+t] = sum_c (stu-nk)*nk*W_out[c] + b_out ; one wave per row.
// ---------------------------------------------------------------------------
__global__ void res_kernel(const float* __restrict__ stu, const float* __restrict__ nk,
                           const float* __restrict__ Wout, const float* __restrict__ bout,
                           float* __restrict__ res) {
  const int row = blockIdx.x * 4 + (threadIdx.x >> 6);
  const int lane = threadIdx.x & 63;
  const float* sp = stu + (size_t)row * 256;
  const float* np = nk + (size_t)row * 256;
  float s = 0.0f;
#pragma unroll
  for (int j = 0; j < 4; ++j) {
    const int c = j * 64 + lane;
    const float nv = np[c];
    s += (sp[c] - nv) * nv * Wout[c];
  }
#pragma unroll
  for (int o = 32; o > 0; o >>= 1) s += __shfl_down(s, o, 64);
  if (lane == 0) res[row] = s + bout[0];
}

// ---------------------------------------------------------------------------
extern "C" void kernel_launch(void* const* d_in, const int* in_sizes, int n_in,
                              void* d_out, int out_size, void* d_ws, size_t ws_size,
                              hipStream_t stream) {
  const float* q_hot = (const float*)d_in[0];
  const int* result = (const int*)d_in[1];
  const float* next_q = (const float*)d_in[2];
  // d_in[3] = concept_num (unused, compile-time constant 256)
  const float* W_kc = (const float*)d_in[4];
  const float* b_kc = (const float*)d_in[5];
  const float* W_ih = (const float*)d_in[6];
  const float* W_hh = (const float*)d_in[7];
  const float* b_ih = (const float*)d_in[8];
  const float* b_hh = (const float*)d_in[9];
  const float* W_state = (const float*)d_in[10];
  const float* b_state = (const float*)d_in[11];
  const float* W_out = (const float*)d_in[12];
  const float* b_out = (const float*)d_in[13];

  float* out_res = (float*)d_out;       // 12800 fp32
  float* out_stu = out_res + 12800;     // 12800*256 fp32

  char* ws = (char*)d_ws;
  u16* kcv = (u16*)(ws);                        // 12800*512 bf16  = 13,107,200 B
  float* nk = (float*)(ws + 13107200);          // 12800*256 fp32  = 13,107,200 B
  u16* hseq = (u16*)(ws + 26214400);            // 201*65536 bf16  = 26,345,472 B
  u16* Whh_bf = (u16*)(ws + 52559872);          // 4096*1024 bf16  =  8,388,608 B
  u16* Wih_bf = (u16*)(ws + 60948480);          // 4096*512 bf16   =  4,194,304 B
  u16* Wkc_bf = (u16*)(ws + 65142784);          // 256*1024 bf16   =    524,288 B
  u16* Wst_bf = (u16*)(ws + 65667072);          // 256*1024 bf16   =    524,288 B
  unsigned* cnt = (unsigned*)(ws + 66191360);   // 128 u32 = 512 B (4 used, 64B apart)
  u16* gx = (u16*)(ws + 66192384);              // 12800*4096 bf16 = 104,857,600 B
  // q_bf/nq_bf alias the gx region (dead before gx is written)
  u16* q_bf = gx;                               // 12800*1024 bf16 = 26,214,400 B
  u16* nq_bf = gx + 13107200;                   // 12800*1024 bf16
  // total ws footprint: 171,049,984 B

  // fp32 -> bf16 conversions
  cvt_kernel<<<dim3(12800), 256, 0, stream>>>(q_hot, q_bf);
  cvt_kernel<<<dim3(12800), 256, 0, stream>>>(next_q, nq_bf);
  cvt_kernel<<<dim3(256), 256, 0, stream>>>(W_kc, Wkc_bf);
  cvt_kernel<<<dim3(2048), 256, 0, stream>>>(W_ih, Wih_bf);
  cvt_kernel<<<dim3(4096), 256, 0, stream>>>(W_hh, Whh_bf);
  cvt_kernel<<<dim3(256), 256, 0, stream>>>(W_state, Wst_bf);

  init_kernel<<<dim3(64), 256, 0, stream>>>(hseq, cnt);
  gemm_bt<EpiKcVec><<<dim3(100, 2), 256, 0, stream>>>(q_bf, Wkc_bf, 12800, 256, 1024,
                                                      EpiKcVec{b_kc, result, kcv});
  gemm_bt<EpiNk><<<dim3(100, 2), 256, 0, stream>>>(nq_bf, Wkc_bf, 12800, 256, 1024,
                                                   EpiNk{b_kc, nk});
  gemm_bt<EpiGx><<<dim3(100, 32), 256, 0, stream>>>(kcv, Wih_bf, 12800, 4096, 512,
                                                    EpiGx{b_ih, b_hh, gx});
  lstm_scan<<<dim3(64), 1024, 0, stream>>>(Whh_bf, gx, hseq, cnt);
  gemm_bt<EpiStu><<<dim3(100, 2), 256, 0, stream>>>(hseq + 65536, Wst_bf, 12800, 256, 1024,
                                                    EpiStu{b_state, out_stu});
  res_kernel<<<dim3(3200), 256, 0, stream>>>(out_stu, nk, W_out, b_out, out_res);
}

// Round 6
// 1361.124 us; speedup vs baseline: 3.0602x; 3.0602x over previous
//
#include <hip/hip_runtime.h>
#include <math.h>

// ---------------------------------------------------------------------------
// RNN knowledge-tracing model, MI355X (gfx950).
// B=64, T=200, SKILLS=1024, C=256, H=1024.  ALL external I/O is fp32.
// Internal compute uses bf16 MFMA with fp32 accumulation.
// Round 11: revert to r8 geometry (r9/r10's 1024-thread block capped the
// unified VGPR/AGPR budget at 128/wave -> bfrag[32] spilled to scratch,
// VGPR_Count 64, 4x slowdown).  On top of r8 (proven 940us, VGPR 92):
//   * Per-wave REGISTER publish: each wave packs its two batch-rows via
//     2 shfl_xor; 16 lanes issue returning exchanges straight from regs.
//     hbuf + one __syncthreads deleted; publish parallel across 8 waves
//     (was wave0-serial 128 exchanges after an LDS round-trip).
//   * Intra-block completion via LDS counter: after per-wave vmcnt(0),
//     lane0 adds to scnt[t]; the wave seeing prev==7 stores the block
//     flag.  Global protocol = r8's proven 32-flag scheme (parallel
//     stores, distinct addresses — none of r9's same-address RMW storm).
//   * Bounded flag poll (hang insurance), sc0 sc1 16B staging, 4-chain
//     MFMA split, gx prefetch under MFMA: all kept from r8/r10.
// ---------------------------------------------------------------------------

typedef unsigned short u16;
typedef unsigned long long u64;
typedef __bf16 bf16x8 __attribute__((ext_vector_type(8)));
typedef float floatx4 __attribute__((ext_vector_type(4)));
typedef unsigned int u32x4 __attribute__((ext_vector_type(4)));

__device__ __forceinline__ float bf2f(u16 h) {
  unsigned int u = ((unsigned int)h) << 16;
  float f;
  __builtin_memcpy(&f, &u, 4);
  return f;
}
__device__ __forceinline__ u16 f2bf(float f) {
  unsigned int u;
  __builtin_memcpy(&u, &f, 4);
  u += 0x7FFFu + ((u >> 16) & 1u);  // RNE
  return (u16)(u >> 16);
}
__device__ __forceinline__ float sigm(float x) { return 1.0f / (1.0f + __expf(-x)); }

// --- fp32 -> bf16 convert, float4 vectorized; exact grid (n % 1024 == 0) ---
__global__ void cvt_kernel(const float* __restrict__ in, u16* __restrict__ out) {
  const int i = blockIdx.x * 256 + threadIdx.x;
  const float4 v = ((const float4*)in)[i];
  ushort4 o;
  o.x = f2bf(v.x);
  o.y = f2bf(v.y);
  o.z = f2bf(v.z);
  o.w = f2bf(v.w);
  ((ushort4*)out)[i] = o;
}

// ---------------------------------------------------------------------------
// Generic 128x128-tile bf16 GEMM, C = A[M,K] @ B[N,K]^T, epilogue functor.
// ---------------------------------------------------------------------------
template <class Epi>
__global__ __launch_bounds__(256, 2) void gemm_bt(const u16* __restrict__ A,
                                                  const u16* __restrict__ B,
                                                  int M, int N, int K, Epi epi) {
  __shared__ u16 As[128 * 32];
  __shared__ u16 Bs[128 * 32];
  const int tid = threadIdx.x;
  const int w = tid >> 6, lane = tid & 63;
  const int wm = w & 1, wn = w >> 1;
  const int bm = blockIdx.x * 128, bn = blockIdx.y * 128;
  const int lrow = lane & 15, lk8 = (lane >> 4) * 8;
  const int srow = lane >> 2;        // staging: row within 16-row segment
  const int skc = (lane & 3) * 8;    // staging: k chunk (8 bf16 = 16B)

  floatx4 acc[4][4] = {};

  for (int k0 = 0; k0 < K; k0 += 32) {
#pragma unroll
    for (int r = 0; r < 2; ++r) {
      const int seg = w * 2 + r;  // 8 segments of 16 rows x 32 k
      const int row = seg * 16 + srow;
      __builtin_amdgcn_global_load_lds(
          (const __attribute__((address_space(1))) unsigned int*)(A + (size_t)(bm + row) * K + k0 + skc),
          (__attribute__((address_space(3))) unsigned int*)(As + seg * 512), 16, 0, 0);
      __builtin_amdgcn_global_load_lds(
          (const __attribute__((address_space(1))) unsigned int*)(B + (size_t)(bn + row) * K + k0 + skc),
          (__attribute__((address_space(3))) unsigned int*)(Bs + seg * 512), 16, 0, 0);
    }
    __syncthreads();

    bf16x8 af[4], bfr[4];
#pragma unroll
    for (int i = 0; i < 4; ++i) {
      af[i] = *(const bf16x8*)(As + (wm * 64 + i * 16 + lrow) * 32 + lk8);
      bfr[i] = *(const bf16x8*)(Bs + (wn * 64 + i * 16 + lrow) * 32 + lk8);
    }
#pragma unroll
    for (int i = 0; i < 4; ++i)
#pragma unroll
      for (int j = 0; j < 4; ++j)
        acc[i][j] = __builtin_amdgcn_mfma_f32_16x16x32_bf16(af[i], bfr[j], acc[i][j], 0, 0, 0);
    __syncthreads();
  }

  // C/D layout: col = lane&15, row = (lane>>4)*4 + reg  [verified m89/m91]
  const int rbase = bm + wm * 64 + (lane >> 4) * 4;
  const int cbase = bn + wn * 64 + lrow;
#pragma unroll
  for (int i = 0; i < 4; ++i)
#pragma unroll
    for (int j = 0; j < 4; ++j)
#pragma unroll
      for (int r = 0; r < 4; ++r)
        epi(rbase + i * 16 + r, cbase + j * 16, acc[i][j][r]);
}

// --- epilogues --------------------------------------------------------------
struct EpiKcVec {  // rows are b*200+t; scatter into [row][512] by result mask
  const float* bkc;
  const int* result;
  u16* kcv;
  __device__ void operator()(int row, int col, float v) const {
    v += bkc[col];
    const int off = (result[row] == 1) ? 0 : 256;
    const size_t base = (size_t)row * 512;
    kcv[base + off + col] = f2bf(v);
    kcv[base + (256 - off) + col] = 0;  // zero half
  }
};
struct EpiNk {
  const float* bkc;
  float* nk;
  __device__ void operator()(int row, int col, float v) const {
    nk[(size_t)row * 256 + col] = v + bkc[col];
  }
};
struct EpiGx {  // input row = b*200+t -> store t-major (t*64+b), bf16
  const float* bih;
  const float* bhh;
  u16* gx;
  __device__ void operator()(int row, int col, float v) const {
    v += bih[col] + bhh[col];
    const int b = row / 200, t = row - b * 200;
    gx[(size_t)(t * 64 + b) * 4096 + col] = f2bf(v);
  }
};
struct EpiStu {  // input row = t*64+b -> store fp32 at (b*200+t)*256+col
  const float* bst;
  float* out;
  __device__ void operator()(int row, int col, float v) const {
    v += bst[col];
    const int b = row & 63, t = row >> 6;
    out[(size_t)(b * 200 + t) * 256 + col] = v;
  }
};

// ---------------------------------------------------------------------------
// init: zero h frame 0 (64x1024 bf16 = 128KB) + 128 barrier flags
// ---------------------------------------------------------------------------
__global__ void init_kernel(u16* hseq, unsigned* flags) {
  const int i = blockIdx.x * 256 + threadIdx.x;  // 64 blocks -> 16384 threads
  ((u64*)hseq)[i] = 0ULL;
  if (blockIdx.x == 0 && threadIdx.x < 128) flags[threadIdx.x] = 0u;
}

// ---------------------------------------------------------------------------
// LSTM scan. 128 blocks x 512 threads = 4 batch-groups x 32 col-groups;
// block owns 16 batches x 32 h-cols. Wave w (0..7): gate g = w&3, col-half
// hf = w>>2; its W_hh slice (16 rows x 1024 K) lives in registers/AGPRs as
// 32 MFMA B-fragments for the whole kernel.
//
// Fence-free h exchange (r8 protocol + per-wave publish):
//   publish (per wave): pack h (rows 2w, 2w+1) into u64 via 2 shfl_xor;
//            lanes (lane&3)==0 issue returning AGENT u64 exchanges (execute
//            at the coherence point); s_waitcnt vmcnt(0); lane0 adds to
//            LDS scnt[t]; the wave seeing prev==7 (all 8 waves drained)
//            stores the block flag (relaxed agent).
//   wait:    wave 0 polls the 32 flags of ITS batch-group (distinct
//            addresses, parallel stores), bounded spin, then __syncthreads.
//   consume: frame quiescent once all group flags >= t -> plain
//            read-through loads (global_load_dwordx4 sc0 sc1) stage it.
// 3 __syncthreads/step (stage, gbuf, release).
// ---------------------------------------------------------------------------
__global__ __launch_bounds__(512, 2) void lstm_scan(const u16* __restrict__ Whh,
                                                    const u16* __restrict__ gx,
                                                    u16* __restrict__ hseq,
                                                    unsigned* __restrict__ flags) {
  __shared__ __align__(16) u16 Ab[16 * 1032];  // +8 pad: 2-way bank alias (free)
  __shared__ float gbuf[4 * 512];
  __shared__ unsigned scnt[200];               // per-step intra-block counters
  const int tid = threadIdx.x;
  const int w = tid >> 6;
  const int lane = tid & 63;
  const int lrow = lane & 15;
  const int lk8 = (lane >> 4) * 8;
  const int g = w & 3;    // gate index (torch order i,f,g,o)
  const int hf = w >> 2;  // col half (0/1) within the block's 32 cols
  const int gb = blockIdx.x >> 5;
  const int gn = blockIdx.x & 31;
  const int bb = gb * 16;
  const int j0 = gn * 32;

  if (tid < 200) scnt[tid] = 0u;  // published before first use by sync below

  // B-fragments: W_hh[g*1024 + j0 + hf*16 + lrow][k] -> 128 regs, loaded once
  bf16x8 bfrag[32];
  {
    const u16* wp = Whh + (size_t)(g * 1024 + j0 + hf * 16 + lrow) * 1024 + lk8;
#pragma unroll
    for (int ks = 0; ks < 32; ++ks) bfrag[ks] = *(const bf16x8*)(wp + ks * 32);
  }

  float c_state = 0.0f;
  const int um = tid >> 5, un = tid & 31;  // update-phase (batch, col) mapping

  // gx fetch: 4 values/thread (batch rows (lane>>4)*4+r, gate g, col hf*16+lrow)
  const u16* gxb =
      gx + (size_t)(bb + (lane >> 4) * 4) * 4096 + g * 1024 + j0 + hf * 16 + lrow;
  u16 gcur[4];
  {
    const u16* gp = gxb;  // t = 0
    gcur[0] = gp[0];
    gcur[1] = gp[4096];
    gcur[2] = gp[8192];
    gcur[3] = gp[12288];
  }

  for (int t = 0; t < 200; ++t) {
    // ---- stage h[t] rows bb..bb+15 (32KB) via coherent 16B loads ----
    {
      const char* hb = (const char*)(hseq + (size_t)t * 65536 + (size_t)bb * 1024);
      const char* p0 = hb + tid * 16;
      const char* p1 = p0 + 8192;
      const char* p2 = p0 + 16384;
      const char* p3 = p0 + 24576;
      u32x4 t0, t1, t2, t3;
      asm volatile(
          "global_load_dwordx4 %0, %4, off sc0 sc1\n\t"
          "global_load_dwordx4 %1, %5, off sc0 sc1\n\t"
          "global_load_dwordx4 %2, %6, off sc0 sc1\n\t"
          "global_load_dwordx4 %3, %7, off sc0 sc1\n\t"
          "s_waitcnt vmcnt(0)"
          : "=&v"(t0), "=&v"(t1), "=&v"(t2), "=&v"(t3)
          : "v"(p0), "v"(p1), "v"(p2), "v"(p3)
          : "memory");
      // chunk ch = jj*512 + tid: row = ch>>7 (128 chunks/row), col8 = (ch&127)*8
      {
        const int ch = tid;
        *(u32x4*)(Ab + (ch >> 7) * 1032 + (ch & 127) * 8) = t0;
      }
      {
        const int ch = 512 + tid;
        *(u32x4*)(Ab + (ch >> 7) * 1032 + (ch & 127) * 8) = t1;
      }
      {
        const int ch = 1024 + tid;
        *(u32x4*)(Ab + (ch >> 7) * 1032 + (ch & 127) * 8) = t2;
      }
      {
        const int ch = 1536 + tid;
        *(u32x4*)(Ab + (ch >> 7) * 1032 + (ch & 127) * 8) = t3;
      }
    }
    __syncthreads();

    // acc init = gx (includes b_ih+b_hh); D layout col=lane&15, row=(lane>>4)*4+r
    floatx4 a0, a1 = {}, a2 = {}, a3 = {};
    a0[0] = bf2f(gcur[0]);
    a0[1] = bf2f(gcur[1]);
    a0[2] = bf2f(gcur[2]);
    a0[3] = bf2f(gcur[3]);

    // prefetch gx for t+1 now: HBM latency hides under the MFMA section
    if (t < 199) {
      const u16* gp = gxb + (size_t)(t + 1) * 262144;
      gcur[0] = gp[0];
      gcur[1] = gp[4096];
      gcur[2] = gp[8192];
      gcur[3] = gp[12288];
    }

    // 4 independent accumulator chains (dep chain 32 -> 8)
#pragma unroll
    for (int ks = 0; ks < 32; ks += 4) {
      const u16* ap = Ab + lrow * 1032 + ks * 32 + lk8;
      a0 = __builtin_amdgcn_mfma_f32_16x16x32_bf16(*(const bf16x8*)(ap), bfrag[ks], a0, 0, 0, 0);
      a1 = __builtin_amdgcn_mfma_f32_16x16x32_bf16(*(const bf16x8*)(ap + 32), bfrag[ks + 1], a1, 0, 0, 0);
      a2 = __builtin_amdgcn_mfma_f32_16x16x32_bf16(*(const bf16x8*)(ap + 64), bfrag[ks + 2], a2, 0, 0, 0);
      a3 = __builtin_amdgcn_mfma_f32_16x16x32_bf16(*(const bf16x8*)(ap + 96), bfrag[ks + 3], a3, 0, 0, 0);
    }
    const floatx4 acc = (a0 + a1) + (a2 + a3);
    {
      const int mrow = (lane >> 4) * 4;
#pragma unroll
      for (int r = 0; r < 4; ++r)
        gbuf[g * 512 + (mrow + r) * 32 + hf * 16 + lrow] = acc[r];
    }
    __syncthreads();

    // update phase: thread -> (batch row um, col un); rows 2w,2w+1 in wave w
    const float gi = gbuf[um * 32 + un];
    const float gf = gbuf[512 + um * 32 + un];
    const float gg = gbuf[1024 + um * 32 + un];
    const float go = gbuf[1536 + um * 32 + un];
    c_state = sigm(gf) * c_state + sigm(gi) * tanhf(gg);
    const float h = sigm(go) * tanhf(c_state);

    // ---- publish h[t+1] from registers, per wave (16 exchanges/wave) ----
    {
      const unsigned hb16 = (unsigned)f2bf(h);
      const unsigned nb = (unsigned)__shfl_xor((int)hb16, 1, 64);
      const unsigned lo = (lane & 1) ? (nb | (hb16 << 16)) : (hb16 | (nb << 16));
      const unsigned hi = (unsigned)__shfl_xor((int)lo, 2, 64);
      if ((lane & 3) == 0) {  // 16 lanes: 8 words per row, 2 rows
        const u64 word = (u64)lo | ((u64)hi << 32);
        u64* dst = (u64*)(hseq + (size_t)(t + 1) * 65536 +
                          (size_t)(bb + um) * 1024 + j0) + ((lane & 31) >> 2);
        u64 old = __hip_atomic_exchange(dst, word, __ATOMIC_RELAXED,
                                        __HIP_MEMORY_SCOPE_AGENT);
        asm volatile("" ::"v"(old));  // force sc0 (returning) form
      }
      asm volatile("s_waitcnt vmcnt(0)" ::: "memory");  // returns back => at IC
      if (lane == 0) {
        const unsigned prev = atomicAdd(&scnt[t], 1u);
        if (prev == 7u)  // last of the block's 8 waves to drain
          __hip_atomic_store(&flags[blockIdx.x], (unsigned)(t + 1),
                             __ATOMIC_RELAXED, __HIP_MEMORY_SCOPE_AGENT);
      }
    }

    // ---- wait: wave 0 polls own batch-group's 32 flags (bounded) ----
    if (w == 0) {
      const unsigned tgt = (unsigned)(t + 1);
      const unsigned* gfp = &flags[gb * 32 + (lane & 31)];
      for (unsigned spin = 0; spin < (1u << 20); ++spin) {
        const unsigned v = __hip_atomic_load(gfp, __ATOMIC_RELAXED,
                                             __HIP_MEMORY_SCOPE_AGENT);
        if (__all(v >= tgt)) break;
        __builtin_amdgcn_s_sleep(1);
      }
    }
    __syncthreads();
  }
}

// ---------------------------------------------------------------------------
// res[b*200+t] = sum_c (stu-nk)*nk*W_out[c] + b_out ; one wave per row.
// ---------------------------------------------------------------------------
__global__ void res_kernel(const float* __restrict__ stu, const float* __restrict__ nk,
                           const float* __restrict__ Wout, const float* __restrict__ bout,
                           float* __restrict__ res) {
  const int row = blockIdx.x * 4 + (threadIdx.x >> 6);
  const int lane = threadIdx.x & 63;
  const float* sp = stu + (size_t)row * 256;
  const float* np = nk + (size_t)row * 256;
  float s = 0.0f;
#pragma unroll
  for (int j = 0; j < 4; ++j) {
    const int c = j * 64 + lane;
    const float nv = np[c];
    s += (sp[c] - nv) * nv * Wout[c];
  }
#pragma unroll
  for (int o = 32; o > 0; o >>= 1) s += __shfl_down(s, o, 64);
  if (lane == 0) res[row] = s + bout[0];
}

// ---------------------------------------------------------------------------
extern "C" void kernel_launch(void* const* d_in, const int* in_sizes, int n_in,
                              void* d_out, int out_size, void* d_ws, size_t ws_size,
                              hipStream_t stream) {
  const float* q_hot = (const float*)d_in[0];
  const int* result = (const int*)d_in[1];
  const float* next_q = (const float*)d_in[2];
  // d_in[3] = concept_num (unused, compile-time constant 256)
  const float* W_kc = (const float*)d_in[4];
  const float* b_kc = (const float*)d_in[5];
  const float* W_ih = (const float*)d_in[6];
  const float* W_hh = (const float*)d_in[7];
  const float* b_ih = (const float*)d_in[8];
  const float* b_hh = (const float*)d_in[9];
  const float* W_state = (const float*)d_in[10];
  const float* b_state = (const float*)d_in[11];
  const float* W_out = (const float*)d_in[12];
  const float* b_out = (const float*)d_in[13];

  float* out_res = (float*)d_out;       // 12800 fp32
  float* out_stu = out_res + 12800;     // 12800*256 fp32

  char* ws = (char*)d_ws;
  u16* kcv = (u16*)(ws);                        // 12800*512 bf16  = 13,107,200 B
  float* nk = (float*)(ws + 13107200);          // 12800*256 fp32  = 13,107,200 B
  u16* hseq = (u16*)(ws + 26214400);            // 201*65536 bf16  = 26,345,472 B
  u16* Whh_bf = (u16*)(ws + 52559872);          // 4096*1024 bf16  =  8,388,608 B
  u16* Wih_bf = (u16*)(ws + 60948480);          // 4096*512 bf16   =  4,194,304 B
  u16* Wkc_bf = (u16*)(ws + 65142784);          // 256*1024 bf16   =    524,288 B
  u16* Wst_bf = (u16*)(ws + 65667072);          // 256*1024 bf16   =    524,288 B
  unsigned* flags = (unsigned*)(ws + 66191360); // 128 u32 = 512 B
  u16* gx = (u16*)(ws + 66192384);              // 12800*4096 bf16 = 104,857,600 B
  // q_bf/nq_bf alias the gx region (dead before gx is written)
  u16* q_bf = gx;                               // 12800*1024 bf16 = 26,214,400 B
  u16* nq_bf = gx + 13107200;                   // 12800*1024 bf16
  // total ws footprint: 171,049,984 B

  // fp32 -> bf16 conversions
  cvt_kernel<<<dim3(12800), 256, 0, stream>>>(q_hot, q_bf);
  cvt_kernel<<<dim3(12800), 256, 0, stream>>>(next_q, nq_bf);
  cvt_kernel<<<dim3(256), 256, 0, stream>>>(W_kc, Wkc_bf);
  cvt_kernel<<<dim3(2048), 256, 0, stream>>>(W_ih, Wih_bf);
  cvt_kernel<<<dim3(4096), 256, 0, stream>>>(W_hh, Whh_bf);
  cvt_kernel<<<dim3(256), 256, 0, stream>>>(W_state, Wst_bf);

  init_kernel<<<dim3(64), 256, 0, stream>>>(hseq, flags);
  gemm_bt<EpiKcVec><<<dim3(100, 2), 256, 0, stream>>>(q_bf, Wkc_bf, 12800, 256, 1024,
                                                      EpiKcVec{b_kc, result, kcv});
  gemm_bt<EpiNk><<<dim3(100, 2), 256, 0, stream>>>(nq_bf, Wkc_bf, 12800, 256, 1024,
                                                   EpiNk{b_kc, nk});
  gemm_bt<EpiGx><<<dim3(100, 32), 256, 0, stream>>>(kcv, Wih_bf, 12800, 4096, 512,
                                                    EpiGx{b_ih, b_hh, gx});
  lstm_scan<<<dim3(128), 512, 0, stream>>>(Whh_bf, gx, hseq, flags);
  gemm_bt<EpiStu><<<dim3(100, 2), 256, 0, stream>>>(hseq + 65536, Wst_bf, 12800, 256, 1024,
                                                    EpiStu{b_state, out_stu});
  res_kernel<<<dim3(3200), 256, 0, stream>>>(out_stu, nk, W_out, b_out, out_res);
}